// Round 3
// baseline (232.938 us; speedup 1.0000x reference)
//
#include <hip/hip_runtime.h>

// PointCloudCompletionLoss — fused Chamfer-L2, Gram-trick inner loop.
// d(x,y) = |x|^2 + (|y|^2 - 2 x.y); min over y of t = |y|^2 - 2 x.y needs only
// 3 fma (tile stages {-2y, |y|^2}); |x|^2 added after the min (so d >= 0 and
// uint-bit atomicMin remains order-correct). Two t's per v_min3_f32.
// Single kernel: last block (ticket) reduces the mins array and writes out.
constexpr int NMINS = 102400;          // 4096 + 3*32768 directed mins
constexpr int NBLK  = 2304;            // 9216 waves / 4

__global__ __launch_bounds__(256) void pccl_stage(
    const float* __restrict__ Xc, const float* __restrict__ Xf,
    const float* __restrict__ G,
    const int* __restrict__ pc, const int* __restrict__ pf,
    unsigned* __restrict__ mins, unsigned* __restrict__ counter,
    float* __restrict__ out)
{
    __shared__ float4 yb[4][256];   // per-wave Y tile: {-2y0,-2y1,-2y2,|y|^2}
    const int wv   = __builtin_amdgcn_readfirstlane(threadIdx.x >> 6);
    const int lane = threadIdx.x & 63;
    const int W    = blockIdx.x * 4 + wv;

    // pass decode: p0 coarse->gt, p1 gt->coarse, p2 fine->gt, p3 gt->fine
    const float* Xp; const float* Yp;
    int NX, NY, lx, local, mbase;
    if (W < 512)        { Xp = Xc; Yp = G;  NX = 1024; NY = 8192; lx = 2; local = W;        mbase = 0; }
    else if (W < 1024)  { Xp = G;  Yp = Xc; NX = 8192; NY = 1024; lx = 5; local = W - 512;  mbase = 4096; }
    else if (W < 5120)  { Xp = Xf; Yp = G;  NX = 8192; NY = 8192; lx = 5; local = W - 1024; mbase = 36864; }
    else                { Xp = G;  Yp = Xf; NX = 8192; NY = 8192; lx = 5; local = W - 5120; mbase = 69632; }
    const int xt   = local & ((1 << (lx + 2)) - 1);  // batch*xtile
    const int sp   = local >> (lx + 2);              // Y-split index
    const int b    = xt >> lx;
    const int xoff = (xt & ((1 << lx) - 1)) << 8;

    // ---- stage 256 Y points as {-2y, |y|^2} (wave-local, no barrier) ----
    const float* ys = Yp + ((size_t)b * NY + (size_t)sp * 256) * 3;
    #pragma unroll
    for (int k = 0; k < 4; ++k) {
        const int i = lane + 64 * k;
        const float y0 = ys[i * 3 + 0], y1 = ys[i * 3 + 1], y2 = ys[i * 3 + 2];
        const float w  = y0 * y0 + y1 * y1 + y2 * y2;
        yb[wv][i] = make_float4(-2.f * y0, -2.f * y1, -2.f * y2, w);
    }

    // ---- X coords + |x|^2 in registers: 4 X points per lane ----
    float x0[4], x1[4], x2[4], x2s[4], best[4];
    const float* xs = Xp + ((size_t)b * NX + xoff) * 3;
    #pragma unroll
    for (int k = 0; k < 4; ++k) {
        const int xi = lane + 64 * k;
        x0[k] = xs[xi * 3 + 0];
        x1[k] = xs[xi * 3 + 1];
        x2[k] = xs[xi * 3 + 2];
        x2s[k] = x0[k] * x0[k] + x1[k] * x1[k] + x2[k] * x2[k];
        best[k] = 3.0e38f;
    }

    // ---- inner: 3 fma + 1/2 min per pair ----
    #pragma unroll 4
    for (int j = 0; j < 256; j += 2) {
        const float4 ya = yb[wv][j];
        const float4 yc = yb[wv][j + 1];
        #pragma unroll
        for (int k = 0; k < 4; ++k) {
            const float t0 = fmaf(x0[k], ya.x, fmaf(x1[k], ya.y, fmaf(x2[k], ya.z, ya.w)));
            const float t1 = fmaf(x0[k], yc.x, fmaf(x1[k], yc.y, fmaf(x2[k], yc.z, yc.w)));
            best[k] = fminf(fminf(best[k], t0), t1);   // -> v_min3_f32
        }
    }

    unsigned* mp = mins + mbase + b * NX + xoff;
    #pragma unroll
    for (int k = 0; k < 4; ++k) {
        const float d = fmaxf(x2s[k] + best[k], 0.0f);  // d >= 0 -> uint order ok
        atomicMin(mp + lane + 64 * k, __float_as_uint(d));
    }

    // ---- last-block-out finalize ----
    __threadfence();
    __syncthreads();
    __shared__ unsigned sticket;
    if (threadIdx.x == 0) sticket = atomicAdd(counter, 1u);
    __syncthreads();
    if (sticket != NBLK - 1) return;
    __threadfence();

    float s[4] = {0.f, 0.f, 0.f, 0.f};
    for (int it = 0; it < NMINS / 256; ++it) {
        const int i = it * 256 + threadIdx.x;
        const float v = __uint_as_float(atomicOr(&mins[i], 0u));  // coherent read
        const int seg = (it < 16) ? 0 : (it < 144) ? 1 : (it < 272) ? 2 : 3;
        s[seg] += v;
    }
    #pragma unroll
    for (int c = 0; c < 4; ++c) {
        #pragma unroll
        for (int off = 32; off > 0; off >>= 1)
            s[c] += __shfl_down(s[c], off, 64);
    }
    __shared__ float sm[4][4];
    if (lane == 0) {
        sm[wv][0] = s[0]; sm[wv][1] = s[1]; sm[wv][2] = s[2]; sm[wv][3] = s[3];
    }
    __syncthreads();
    if (threadIdx.x == 0) {
        const float S0 = sm[0][0] + sm[1][0] + sm[2][0] + sm[3][0];
        const float S1 = sm[0][1] + sm[1][1] + sm[2][1] + sm[3][1];
        const float S2 = sm[0][2] + sm[1][2] + sm[2][2] + sm[3][2];
        const float S3 = sm[0][3] + sm[1][3] + sm[2][3] + sm[3][3];
        out[0] = (S0 * (1.f / 4096.f) + S1 * (1.f / 32768.f)) * (float)pc[0];
        out[1] = ((S2 + S3) * (1.f / 32768.f)) * (float)pf[0];
    }
}

extern "C" void kernel_launch(void* const* d_in, const int* in_sizes, int n_in,
                              void* d_out, int out_size, void* d_ws, size_t ws_size,
                              hipStream_t stream) {
    const float* coarse = (const float*)d_in[0];
    const float* fine   = (const float*)d_in[1];
    const float* gt     = (const float*)d_in[2];
    const int*   pc     = (const int*)d_in[3];
    const int*   pf     = (const int*)d_in[4];
    float* out = (float*)d_out;

    unsigned* mins    = (unsigned*)d_ws;
    unsigned* counter = mins + NMINS;

    // 0x7F7F7F7F as float = 3.396e38: valid +inf substitute for uint-bit min
    hipMemsetAsync(mins, 0x7F, (size_t)NMINS * 4, stream);
    hipMemsetAsync(counter, 0, 4, stream);
    pccl_stage<<<NBLK, 256, 0, stream>>>(coarse, fine, gt, pc, pf, mins, counter, out);
}

// Round 4
// 115.957 us; speedup vs baseline: 2.0088x; 2.0088x over previous
//
#include <hip/hip_runtime.h>

// PointCloudCompletionLoss — fused Chamfer-L2, Gram-trick, 8 X/thread.
// d(x,y) = |x|^2 + t,  t = |y|^2 - 2 x.y  (3 fma; tile stages {-2y, |y|^2}).
// |x|^2 added after the min over y, so d >= 0 and uint-bit atomicMin is
// order-correct. Y processed in pairs -> fmin(fmin(b,t0),t1) = v_min3.
// 8 X points per lane (512 X per wave) restores the VALU:LDS ratio that
// measured 91% VALUBusy in round 2 (28 VALU instr per ds_read_b128), at
// half the VALU per pair. Reduction is a separate small kernel (no serial
// last-block tail).
constexpr int NMINS = 102400;        // 4096 + 3*32768 directed mins
constexpr int NBLK  = 1152;          // 4608 waves / 4

// Directed passes (X -> min over Y), 512 X per wave, 256-Y splits:
//  p0: coarse(4096)->gt    xtiles  8  splits 32  waves  256  mins[    0..4096)
//  p1: gt(32768)->coarse   xtiles 64  splits  4  waves  256  mins[ 4096..36864)
//  p2: fine(32768)->gt     xtiles 64  splits 32  waves 2048  mins[36864..69632)
//  p3: gt(32768)->fine     xtiles 64  splits 32  waves 2048  mins[69632..102400)

__global__ __launch_bounds__(256) void pccl_stage(
    const float* __restrict__ Xc, const float* __restrict__ Xf,
    const float* __restrict__ G, unsigned* __restrict__ mins)
{
    __shared__ float4 yb[4][256];   // per-wave Y tile: {-2y0,-2y1,-2y2,|y|^2}
    const int wv   = __builtin_amdgcn_readfirstlane(threadIdx.x >> 6);
    const int lane = threadIdx.x & 63;
    const int W    = blockIdx.x * 4 + wv;

    const float* Xp; const float* Yp;
    int NX, NY, lx, local, mbase;
    if (W < 256)        { Xp = Xc; Yp = G;  NX = 1024; NY = 8192; lx = 1; local = W;        mbase = 0; }
    else if (W < 512)   { Xp = G;  Yp = Xc; NX = 8192; NY = 1024; lx = 4; local = W - 256;  mbase = 4096; }
    else if (W < 2560)  { Xp = Xf; Yp = G;  NX = 8192; NY = 8192; lx = 4; local = W - 512;  mbase = 36864; }
    else                { Xp = G;  Yp = Xf; NX = 8192; NY = 8192; lx = 4; local = W - 2560; mbase = 69632; }
    const int xt   = local & ((1 << (lx + 2)) - 1);  // batch * xtile
    const int sp   = local >> (lx + 2);              // Y-split index
    const int b    = xt >> lx;
    const int xoff = (xt & ((1 << lx) - 1)) << 9;    // * 512

    // ---- stage 256 Y points as {-2y, |y|^2} (wave-local, no barrier) ----
    const float* ys = Yp + ((size_t)b * NY + (size_t)sp * 256) * 3;
    #pragma unroll
    for (int k = 0; k < 4; ++k) {
        const int i = lane + 64 * k;
        const float y0 = ys[i * 3 + 0], y1 = ys[i * 3 + 1], y2 = ys[i * 3 + 2];
        const float w  = y0 * y0 + y1 * y1 + y2 * y2;
        yb[wv][i] = make_float4(-2.f * y0, -2.f * y1, -2.f * y2, w);
    }

    // ---- X coords in registers: 8 X points per lane ----
    float x0[8], x1[8], x2[8], best[8];
    const float* xs = Xp + ((size_t)b * NX + xoff) * 3;
    #pragma unroll
    for (int k = 0; k < 8; ++k) {
        const int xi = lane + 64 * k;
        x0[k] = xs[xi * 3 + 0];
        x1[k] = xs[xi * 3 + 1];
        x2[k] = xs[xi * 3 + 2];
        best[k] = 3.0e38f;
    }

    // ---- inner: per Y-pair per X: 6 fma + 1 min3  (28 VALU per b128) ----
    #pragma unroll 2
    for (int j = 0; j < 256; j += 2) {
        const float4 ya = yb[wv][j];
        const float4 yc = yb[wv][j + 1];
        #pragma unroll
        for (int k = 0; k < 8; ++k) {
            const float t0 = fmaf(x0[k], ya.x, fmaf(x1[k], ya.y, fmaf(x2[k], ya.z, ya.w)));
            const float t1 = fmaf(x0[k], yc.x, fmaf(x1[k], yc.y, fmaf(x2[k], yc.z, yc.w)));
            best[k] = fminf(fminf(best[k], t0), t1);
        }
    }

    // ---- epilogue: d = |x|^2 + min_t, clamp >= 0, uint-bit atomicMin ----
    unsigned* mp = mins + mbase + b * NX + xoff;
    #pragma unroll
    for (int k = 0; k < 8; ++k) {
        const float x2s = x0[k] * x0[k] + x1[k] * x1[k] + x2[k] * x2[k];
        const float d = fmaxf(x2s + best[k], 0.0f);
        atomicMin(mp + lane + 64 * k, __float_as_uint(d));
    }
}

// 100 blocks x 256 threads, uint4 per thread. Each wave's 256 consecutive
// elements lie in one segment (boundaries 4096/36864/69632 are 256-aligned).
__global__ __launch_bounds__(256) void pccl_sum(
    const unsigned* __restrict__ mins,
    const int* __restrict__ pc, const int* __restrict__ pf,
    float* __restrict__ out)
{
    const int tid = blockIdx.x * 256 + threadIdx.x;
    const uint4 v = ((const uint4*)mins)[tid];
    float s = __uint_as_float(v.x) + __uint_as_float(v.y)
            + __uint_as_float(v.z) + __uint_as_float(v.w);
    #pragma unroll
    for (int off = 32; off > 0; off >>= 1) s += __shfl_down(s, off, 64);
    if ((threadIdx.x & 63) == 0) {
        const int i = tid * 4;   // segment base of this wave
        float scale, param; int o;
        if (i < 4096)       { scale = 1.f / 4096.f;  param = (float)pc[0]; o = 0; }
        else if (i < 36864) { scale = 1.f / 32768.f; param = (float)pc[0]; o = 0; }
        else                { scale = 1.f / 32768.f; param = (float)pf[0]; o = 1; }
        atomicAdd(out + o, s * scale * param);
    }
}

extern "C" void kernel_launch(void* const* d_in, const int* in_sizes, int n_in,
                              void* d_out, int out_size, void* d_ws, size_t ws_size,
                              hipStream_t stream) {
    const float* coarse = (const float*)d_in[0];
    const float* fine   = (const float*)d_in[1];
    const float* gt     = (const float*)d_in[2];
    const int*   pc     = (const int*)d_in[3];
    const int*   pf     = (const int*)d_in[4];
    float* out = (float*)d_out;
    unsigned* mins = (unsigned*)d_ws;

    // 0x7F7F7F7F as float = 3.396e38: +inf substitute for uint-bit min
    hipMemsetAsync(mins, 0x7F, (size_t)NMINS * 4, stream);
    hipMemsetAsync(out, 0, 2 * sizeof(float), stream);
    pccl_stage<<<NBLK, 256, 0, stream>>>(coarse, fine, gt, mins);
    pccl_sum<<<NMINS / 1024, 256, 0, stream>>>(mins, pc, pf, out);
}